// Round 5
// baseline (172.377 us; speedup 1.0000x reference)
//
#include <hip/hip_runtime.h>
#include <stdint.h>

#define B_    2
#define CIN   128
#define HIMG  32
#define WIMG  32
#define COUT_ 128
#define PP    1024
#define FTOT  1152
#define NSUB  9
#define NS    8
#define NT    8
#define NROW  18

typedef int v4i __attribute__((ext_vector_type(4)));

// ws layout (bytes) — ~2.54 MB
#define OFF_NORM   0                      // 128 f32
#define OFF_MAXV   512                    // 18 u32
#define OFF_PRM    640                    // 18*2 f32 (inv, bias)
#define OFF_PMODE  800                    // 18 i32 (0=arith, 1=lut fallback)
#define OFF_LUT    1024                   // 18*132 u8
#define OFF_WQP    4096                   // 128*1152 u8
#define OFF_WQN    (4096 + 147456)
#define OFF_XQ     (4096 + 2*147456)      // 2*1024*1152 u8

// ---------------------------------------------------------------------------
// Weight prep: per-o norm, f64 quantization (matches np-f64 golden),
// |wi| magnitudes as u8 per sign: wq[o][f].
// ---------------------------------------------------------------------------
__global__ __launch_bounds__(256) void k_prep_w(const float* __restrict__ w,
                                                float* __restrict__ norm_out,
                                                uint8_t* __restrict__ wqp,
                                                uint8_t* __restrict__ wqn) {
    int o = blockIdx.x, tid = threadIdx.x;
    __shared__ float red[256];
    const float* wo = w + (size_t)o * FTOT;
    float m = 0.f;
    for (int f = tid; f < FTOT; f += 256) m = fmaxf(m, fabsf(wo[f]));
    red[tid] = m;
    __syncthreads();
    for (int s2 = 128; s2 > 0; s2 >>= 1) {
        if (tid < s2) red[tid] = fmaxf(red[tid], red[tid + s2]);
        __syncthreads();
    }
    float norm = red[0];
    if (tid == 0) norm_out[o] = norm;
    for (int f = tid; f < FTOT; f += 256) {
        double wi = rint(((double)wo[f] / (double)norm) * 255.0);
        wqp[(size_t)o * FTOT + f] = (uint8_t)(int)fmax(wi, 0.0);
        wqn[(size_t)o * FTOT + f] = (uint8_t)(int)fmax(-wi, 0.0);
    }
}

// ---------------------------------------------------------------------------
// Input prep: im2col + quantize to u8; also zero the 18 atomicMax slots.
// ---------------------------------------------------------------------------
__global__ __launch_bounds__(256) void k_prep_x(const float* __restrict__ x,
                                                uint8_t* __restrict__ xq,
                                                uint32_t* __restrict__ maxv) {
    if (blockIdx.x == 0 && threadIdx.x < NROW) maxv[threadIdx.x] = 0u;
    int gid = blockIdx.x * 256 + threadIdx.x;    // 2*1024*72 = 147456 exact
    int fg = gid % 72;
    int rest = gid / 72;
    int p = rest & 1023;
    int b = rest >> 10;
    int py = p >> 5, px = p & 31;
    uint32_t dw[4] = {0, 0, 0, 0};
    #pragma unroll
    for (int j = 0; j < 16; ++j) {
        int f = fg * 16 + j;
        int c = f / 9, u = f % 9;
        int kh = u / 3, kw = u % 3;
        int y = py + kh - 1, xx = px + kw - 1;
        uint32_t xi = 0;
        if (y >= 0 && y < HIMG && xx >= 0 && xx < WIMG) {
            float v = x[(((size_t)b * CIN + c) * HIMG + y) * WIMG + xx];
            float q = rintf(v * 256.0f);              // exact: power-of-2 scale
            q = fminf(fmaxf(q, 0.f), 255.f);
            xi = (uint32_t)q;
        }
        dw[j >> 2] |= xi << ((j & 3) * 8);
    }
    *reinterpret_cast<uint4*>(xq + (size_t)((b << 10) + p) * FTOT + fg * 16) =
        make_uint4(dw[0], dw[1], dw[2], dw[3]);
}

// Extract bit `sh` of each packed byte -> 0/1 bytes (i8 MFMA operand fragment).
__device__ __forceinline__ v4i bitsel(uint4 d, int sh) {
    v4i r;
    r[0] = (int)((d.x >> sh) & 0x01010101u);
    r[1] = (int)((d.y >> sh) & 0x01010101u);
    r[2] = (int)((d.z >> sh) & 0x01010101u);
    r[3] = (int)((d.w >> sh) & 0x01010101u);
    return r;
}

// ---------------------------------------------------------------------------
// Pass 1: max pr per (sub, sign) via MFMA. Block(512) = (b,ot,pt), wave = s.
// ---------------------------------------------------------------------------
__global__ __launch_bounds__(512) void k_max(const uint8_t* __restrict__ xq,
                                             const uint8_t* __restrict__ wqp,
                                             const uint8_t* __restrict__ wqn,
                                             uint32_t* __restrict__ maxv) {
    int tid = threadIdx.x, lane = tid & 63, wid = tid >> 6;
    int blk = blockIdx.x;
    int b = blk >> 9, r = blk & 511, ot = r >> 6, pt = r & 63;
    int s = wid;
    int col = lane & 15, kq = lane >> 4;
    int p = pt * 16 + col, oa = ot * 16 + col;
    __shared__ uint32_t smax[8][NSUB][2];

    const uint8_t* xbase = xq + (size_t)((b << 10) + p) * FTOT + kq * 16;
    const uint8_t* wpb = wqp + (size_t)oa * FTOT + kq * 16;
    const uint8_t* wnb = wqn + (size_t)oa * FTOT + kq * 16;

    for (int sub = 0; sub < NSUB; ++sub) {
        int fo = sub * 128;
        uint4 xg0 = *(const uint4*)(xbase + fo);
        uint4 xg1 = *(const uint4*)(xbase + fo + 64);
        v4i bf0 = bitsel(xg0, s), bf1 = bitsel(xg1, s);
        uint4 wp0 = *(const uint4*)(wpb + fo), wp1 = *(const uint4*)(wpb + fo + 64);
        uint4 wn0 = *(const uint4*)(wnb + fo), wn1 = *(const uint4*)(wnb + fo + 64);
        int mp = 0, mn = 0;
        #pragma unroll
        for (int t = 0; t < NT; ++t) {
            v4i acc = {0, 0, 0, 0};
            acc = __builtin_amdgcn_mfma_i32_16x16x64_i8(bitsel(wp0, t), bf0, acc, 0, 0, 0);
            acc = __builtin_amdgcn_mfma_i32_16x16x64_i8(bitsel(wp1, t), bf1, acc, 0, 0, 0);
            mp = max(max(acc[0], acc[1]), max(max(acc[2], acc[3]), mp));
            v4i acn = {0, 0, 0, 0};
            acn = __builtin_amdgcn_mfma_i32_16x16x64_i8(bitsel(wn0, t), bf0, acn, 0, 0, 0);
            acn = __builtin_amdgcn_mfma_i32_16x16x64_i8(bitsel(wn1, t), bf1, acn, 0, 0, 0);
            mn = max(max(acn[0], acn[1]), max(max(acn[2], acn[3]), mn));
        }
        #pragma unroll
        for (int off = 32; off > 0; off >>= 1) {
            mp = max(mp, __shfl_xor(mp, off));
            mn = max(mn, __shfl_xor(mn, off));
        }
        if (lane == 0) { smax[wid][sub][0] = (uint32_t)mp; smax[wid][sub][1] = (uint32_t)mn; }
    }
    __syncthreads();
    if (tid < NROW) {
        int sub = tid >> 1, sg = tid & 1;
        uint32_t m = 0;
        #pragma unroll
        for (int w2 = 0; w2 < 8; ++w2) m = max(m, smax[w2][sub][sg]);
        atomicMax(&maxv[tid], m);
    }
}

// ---------------------------------------------------------------------------
// ADC code, arithmetic form — MUST be the same ops in k_lut (verify) and
// k_adc (use): v_cvt + v_fma + v_rndne. IEEE-deterministic.
// ---------------------------------------------------------------------------
__device__ __forceinline__ float adc_arith(float fpr, float inv, float bias) {
    return rintf(fmaf(fpr, inv, bias));
}

// ---------------------------------------------------------------------------
// k_lut: (1) exact f64 reference codes -> global lut (fallback path),
// (2) search per-row f32 (inv,bias) reproducing the table exactly over
// pr in [0, vmax]; verified exhaustively, first passing candidate wins.
// ---------------------------------------------------------------------------
__global__ void k_lut(const uint32_t* __restrict__ maxv,
                      uint8_t* __restrict__ lut,
                      float* __restrict__ prm,
                      int* __restrict__ pmode) {
    __shared__ uint8_t codes[NROW][132];
    __shared__ int best[NROW];
    int tid = threadIdx.x;
    if (tid < NROW) best[tid] = 0x7fffffff;
    // exact f64 table (identical numerics to the passing rounds)
    for (int e = tid; e < NROW * 129; e += 256) {
        int idx = e / 129, pr = e % 129;
        double vmaxd = fmax((double)maxv[idx], 1e-6);
        double step = vmaxd / 15.0;
        double q = rint((double)pr / step);
        q = fmin(fmax(q, 0.0), 15.0);
        codes[idx][pr] = (uint8_t)q;
        lut[idx * 132 + pr] = (uint8_t)q;
    }
    __syncthreads();

    const int NDI = 13, NBJ = 11, NC = NDI * NBJ;
    const int di[NDI] = {0, -1, 1, -2, 2, -3, 3, -4, 4, -5, 5, -6, 6};
    const float bl[NBJ] = {0.0f,
                           -1.220703125e-4f, 1.220703125e-4f,
                           -2.44140625e-4f,  2.44140625e-4f,
                           -4.8828125e-4f,   4.8828125e-4f,
                           -9.765625e-4f,    9.765625e-4f,
                           -1.953125e-3f,    1.953125e-3f};
    for (int task = tid; task < NROW * NC; task += 256) {
        int row = task / NC, cand = task % NC;
        int vmax = (int)maxv[row];
        float inv0 = (float)(15.0 / fmax((double)vmax, 1e-6));
        float inv = __int_as_float(__float_as_int(inv0) + di[cand % NDI]);
        float bias = bl[cand / NDI];
        bool ok = true;
        for (int pr = 0; pr <= vmax; ++pr) {
            if ((int)adc_arith((float)pr, inv, bias) != (int)codes[row][pr]) { ok = false; break; }
        }
        if (vmax == 0) ok = ((int)adc_arith(0.f, inv, bias) == 0);
        if (ok) atomicMin(&best[row], cand);
    }
    __syncthreads();
    if (tid < NROW) {
        int cand = best[tid];
        if (cand == 0x7fffffff) {
            pmode[tid] = 1;                      // fallback: global-LUT gather
            prm[tid * 2 + 0] = 0.f;
            prm[tid * 2 + 1] = 0.f;
        } else {
            int vmax = (int)maxv[tid];
            float inv0 = (float)(15.0 / fmax((double)vmax, 1e-6));
            pmode[tid] = 0;
            prm[tid * 2 + 0] = __int_as_float(__float_as_int(inv0) + di[cand % NDI]);
            prm[tid * 2 + 1] = bl[cand / NDI];
        }
    }
}

// ---------------------------------------------------------------------------
// Pass 2: MFMA pr -> arithmetic ADC (cvt+fma+rndne) -> exact f32-integer
// weighted sums (folded 2^t constants), int epilogue, f64 final scale.
// ---------------------------------------------------------------------------
__global__ __launch_bounds__(512) void k_adc(const uint8_t* __restrict__ xq,
                                             const uint8_t* __restrict__ wqp,
                                             const uint8_t* __restrict__ wqn,
                                             const uint32_t* __restrict__ maxv,
                                             const uint8_t* __restrict__ lut,
                                             const float* __restrict__ prm,
                                             const int* __restrict__ pmode,
                                             const float* __restrict__ norm,
                                             float* __restrict__ out) {
    int tid = threadIdx.x, lane = tid & 63, wid = tid >> 6;
    int blk = blockIdx.x;
    int b = blk >> 9, r = blk & 511, ot = r >> 6, pt = r & 63;
    int s = wid;
    int col = lane & 15, kq = lane >> 4;
    int p = pt * 16 + col, oa = ot * 16 + col;

    __shared__ int lred[8][64][4];

    const uint8_t* xbase = xq + (size_t)((b << 10) + p) * FTOT + kq * 16;
    const uint8_t* wpb = wqp + (size_t)oa * FTOT + kq * 16;
    const uint8_t* wnb = wqn + (size_t)oa * FTOT + kq * 16;

    int run[4] = {0, 0, 0, 0};
    for (int sub = 0; sub < NSUB; ++sub) {
        int fo = sub * 128;
        uint4 xg0 = *(const uint4*)(xbase + fo);
        uint4 xg1 = *(const uint4*)(xbase + fo + 64);
        v4i bf0 = bitsel(xg0, s), bf1 = bitsel(xg1, s);
        uint4 wp0 = *(const uint4*)(wpb + fo), wp1 = *(const uint4*)(wpb + fo + 64);
        uint4 wn0 = *(const uint4*)(wnb + fo), wn1 = *(const uint4*)(wnb + fo + 64);

        int rowp = sub * 2, rown = sub * 2 + 1;
        float ivp = prm[rowp * 2], bvp = prm[rowp * 2 + 1];
        float ivn = prm[rown * 2], bvn = prm[rown * 2 + 1];
        int fbp = pmode[rowp], fbn = pmode[rown];
        const uint8_t* glp = lut + rowp * 132;
        const uint8_t* gln = lut + rown * 132;
        int vp = (int)maxv[rowp], vn = (int)maxv[rown];

        float Spf[4] = {0.f, 0.f, 0.f, 0.f}, Snf[4] = {0.f, 0.f, 0.f, 0.f};
        #pragma unroll
        for (int t = 0; t < NT; ++t) {
            const float ct = (float)(1 << t);
            v4i acc = {0, 0, 0, 0};
            acc = __builtin_amdgcn_mfma_i32_16x16x64_i8(bitsel(wp0, t), bf0, acc, 0, 0, 0);
            acc = __builtin_amdgcn_mfma_i32_16x16x64_i8(bitsel(wp1, t), bf1, acc, 0, 0, 0);
            if (fbp == 0) {
                #pragma unroll
                for (int i = 0; i < 4; ++i)
                    Spf[i] = fmaf(adc_arith((float)acc[i], ivp, bvp), ct, Spf[i]);
            } else {
                #pragma unroll
                for (int i = 0; i < 4; ++i)
                    Spf[i] = fmaf((float)glp[acc[i]], ct, Spf[i]);
            }
            v4i acn = {0, 0, 0, 0};
            acn = __builtin_amdgcn_mfma_i32_16x16x64_i8(bitsel(wn0, t), bf0, acn, 0, 0, 0);
            acn = __builtin_amdgcn_mfma_i32_16x16x64_i8(bitsel(wn1, t), bf1, acn, 0, 0, 0);
            if (fbn == 0) {
                #pragma unroll
                for (int i = 0; i < 4; ++i)
                    Snf[i] = fmaf(adc_arith((float)acn[i], ivn, bvn), ct, Snf[i]);
            } else {
                #pragma unroll
                for (int i = 0; i < 4; ++i)
                    Snf[i] = fmaf((float)gln[acn[i]], ct, Snf[i]);
            }
        }
        #pragma unroll
        for (int i = 0; i < 4; ++i) {
            int Sp = (int)Spf[i], Sn = (int)Snf[i];          // exact (< 2^24)
            run[i] += vp * (Sp << s) - vn * (Sn << s);
        }
    }
    #pragma unroll
    for (int i = 0; i < 4; ++i) lred[wid][lane][i] = run[i];
    __syncthreads();
    if (tid < 256) {
        int lane2 = tid >> 2, i = tid & 3;
        long long s64 = 0;
        #pragma unroll
        for (int w2 = 0; w2 < 8; ++w2) s64 += (long long)lred[w2][lane2][i];
        int o = ot * 16 + (lane2 >> 4) * 4 + i;      // C/D: row=(lane>>4)*4+reg [m89]
        int pp2 = pt * 16 + (lane2 & 15);            // C/D: col=lane&15
        double v = (double)s64 * (double)norm[o] / 15.0 / 255.0 / 256.0;
        out[((size_t)(b * COUT_ + o)) * PP + pp2] = (float)v;
    }
    if (blk == 0 && tid == 0) out[(size_t)B_ * COUT_ * PP] = 0.0f;   // adc_loss
}

// ---------------------------------------------------------------------------
extern "C" void kernel_launch(void* const* d_in, const int* in_sizes, int n_in,
                              void* d_out, int out_size, void* d_ws, size_t ws_size,
                              hipStream_t stream) {
    const float* x = (const float*)d_in[0];
    const float* w = (const float*)d_in[1];
    float* out = (float*)d_out;
    char* ws = (char*)d_ws;

    float* norm = (float*)(ws + OFF_NORM);
    uint32_t* maxv = (uint32_t*)(ws + OFF_MAXV);
    float* prm = (float*)(ws + OFF_PRM);
    int* pmode = (int*)(ws + OFF_PMODE);
    uint8_t* lut = (uint8_t*)(ws + OFF_LUT);
    uint8_t* wqp = (uint8_t*)(ws + OFF_WQP);
    uint8_t* wqn = (uint8_t*)(ws + OFF_WQN);
    uint8_t* xq  = (uint8_t*)(ws + OFF_XQ);

    k_prep_w<<<128, 256, 0, stream>>>(w, norm, wqp, wqn);
    k_prep_x<<<576, 256, 0, stream>>>(x, xq, maxv);
    k_max<<<1024, 512, 0, stream>>>(xq, wqp, wqn, maxv);
    k_lut<<<1, 256, 0, stream>>>(maxv, lut, prm, pmode);
    k_adc<<<1024, 512, 0, stream>>>(xq, wqp, wqn, maxv, lut, prm, pmode, norm, out);
}

// Round 6
// 146.051 us; speedup vs baseline: 1.1803x; 1.1803x over previous
//
#include <hip/hip_runtime.h>
#include <stdint.h>

#define B_    2
#define CIN   128
#define HIMG  32
#define WIMG  32
#define COUT_ 128
#define PP    1024
#define FTOT  1152
#define NSUB  9
#define NS    8
#define NT    8
#define NROW  18

typedef int v4i __attribute__((ext_vector_type(4)));

// ws layout (bytes) — ~2.66 MB
#define OFF_NORM   0                      // 128 f32
#define OFF_MAXV   512                    // 18 u32
#define OFF_MB     640                    // 18 uint2 (m, b)
#define OFF_PMODE  800                    // 18 i32 (0=int-mad, 1=lut fallback)
#define OFF_LUT    1024                   // 18*132 u8
#define OFF_WQP    4096                   // 128*1152 u8
#define OFF_WQN    (4096 + 147456)
#define OFF_XQ     (4096 + 2*147456)      // 2*1024*1152 u8

// ---------------------------------------------------------------------------
// Weight prep (proven): per-o norm, f64 quantization, |wi| u8 per sign.
// ---------------------------------------------------------------------------
__global__ __launch_bounds__(256) void k_prep_w(const float* __restrict__ w,
                                                float* __restrict__ norm_out,
                                                uint8_t* __restrict__ wqp,
                                                uint8_t* __restrict__ wqn) {
    int o = blockIdx.x, tid = threadIdx.x;
    __shared__ float red[256];
    const float* wo = w + (size_t)o * FTOT;
    float m = 0.f;
    for (int f = tid; f < FTOT; f += 256) m = fmaxf(m, fabsf(wo[f]));
    red[tid] = m;
    __syncthreads();
    for (int s2 = 128; s2 > 0; s2 >>= 1) {
        if (tid < s2) red[tid] = fmaxf(red[tid], red[tid + s2]);
        __syncthreads();
    }
    float norm = red[0];
    if (tid == 0) norm_out[o] = norm;
    for (int f = tid; f < FTOT; f += 256) {
        double wi = rint(((double)wo[f] / (double)norm) * 255.0);
        wqp[(size_t)o * FTOT + f] = (uint8_t)(int)fmax(wi, 0.0);
        wqn[(size_t)o * FTOT + f] = (uint8_t)(int)fmax(-wi, 0.0);
    }
}

// ---------------------------------------------------------------------------
// Input prep (proven): im2col + quantize to u8 xq[b][p][f]; zero maxv.
// ---------------------------------------------------------------------------
__global__ __launch_bounds__(256) void k_prep_x(const float* __restrict__ x,
                                                uint8_t* __restrict__ xq,
                                                uint32_t* __restrict__ maxv) {
    if (blockIdx.x == 0 && threadIdx.x < NROW) maxv[threadIdx.x] = 0u;
    int gid = blockIdx.x * 256 + threadIdx.x;    // 2*1024*72 = 147456 exact
    int fg = gid % 72;
    int rest = gid / 72;
    int p = rest & 1023;
    int b = rest >> 10;
    int py = p >> 5, px = p & 31;
    uint32_t dw[4] = {0, 0, 0, 0};
    #pragma unroll
    for (int j = 0; j < 16; ++j) {
        int f = fg * 16 + j;
        int c = f / 9, u = f % 9;
        int kh = u / 3, kw = u % 3;
        int y = py + kh - 1, xx = px + kw - 1;
        uint32_t xi = 0;
        if (y >= 0 && y < HIMG && xx >= 0 && xx < WIMG) {
            float v = x[(((size_t)b * CIN + c) * HIMG + y) * WIMG + xx];
            float q = rintf(v * 256.0f);              // exact: power-of-2 scale
            q = fminf(fmaxf(q, 0.f), 255.f);
            xi = (uint32_t)q;
        }
        dw[j >> 2] |= xi << ((j & 3) * 8);
    }
    *reinterpret_cast<uint4*>(xq + (size_t)((b << 10) + p) * FTOT + fg * 16) =
        make_uint4(dw[0], dw[1], dw[2], dw[3]);
}

// Extract bit `sh` of each packed byte -> 0/1 bytes (i8 MFMA fragment).
__device__ __forceinline__ v4i bitsel(uint4 d, int sh) {
    v4i r;
    r[0] = (int)((d.x >> sh) & 0x01010101u);
    r[1] = (int)((d.y >> sh) & 0x01010101u);
    r[2] = (int)((d.z >> sh) & 0x01010101u);
    r[3] = (int)((d.w >> sh) & 0x01010101u);
    return r;
}

// ---------------------------------------------------------------------------
// Pass 1: max pr per (sub, sign). Block(256) = one (b,ot,pt) tile, 4 waves;
// wave wid covers ALL 8 s and t in {2*wid, 2*wid+1} (bitsel amortized).
// ---------------------------------------------------------------------------
__global__ __launch_bounds__(256, 3) void k_max(const uint8_t* __restrict__ xq,
                                                const uint8_t* __restrict__ wqp,
                                                const uint8_t* __restrict__ wqn,
                                                uint32_t* __restrict__ maxv) {
    int tid = threadIdx.x, lane = tid & 63, wid = tid >> 6;
    int blk = blockIdx.x;
    int b = blk >> 9, ot = (blk >> 6) & 7, pt = blk & 63;
    int col = lane & 15, kq = lane >> 4;
    int p = pt * 16 + col, oa = ot * 16 + col;
    __shared__ uint32_t smax[4][NSUB][2];

    const uint8_t* xbase = xq + (size_t)((b << 10) + p) * FTOT + kq * 16;
    const uint8_t* wpb = wqp + (size_t)oa * FTOT + kq * 16;
    const uint8_t* wnb = wqn + (size_t)oa * FTOT + kq * 16;

    for (int sub = 0; sub < NSUB; ++sub) {
        int fo = sub * 128;
        uint4 xg0 = *(const uint4*)(xbase + fo);
        uint4 xg1 = *(const uint4*)(xbase + fo + 64);
        v4i bf[NS][2];
        #pragma unroll
        for (int s = 0; s < NS; ++s) { bf[s][0] = bitsel(xg0, s); bf[s][1] = bitsel(xg1, s); }
        uint4 wp0 = *(const uint4*)(wpb + fo), wp1 = *(const uint4*)(wpb + fo + 64);
        uint4 wn0 = *(const uint4*)(wnb + fo), wn1 = *(const uint4*)(wnb + fo + 64);

        int mp = 0, mn = 0;
        #pragma unroll
        for (int tt = 0; tt < 2; ++tt) {
            int t = wid * 2 + tt;
            v4i ap0 = bitsel(wp0, t), ap1 = bitsel(wp1, t);
            v4i an0 = bitsel(wn0, t), an1 = bitsel(wn1, t);
            #pragma unroll
            for (int s = 0; s < NS; ++s) {
                v4i acc = {0, 0, 0, 0};
                acc = __builtin_amdgcn_mfma_i32_16x16x64_i8(ap0, bf[s][0], acc, 0, 0, 0);
                acc = __builtin_amdgcn_mfma_i32_16x16x64_i8(ap1, bf[s][1], acc, 0, 0, 0);
                mp = max(mp, max(max(acc[0], acc[1]), max(acc[2], acc[3])));
                v4i acn = {0, 0, 0, 0};
                acn = __builtin_amdgcn_mfma_i32_16x16x64_i8(an0, bf[s][0], acn, 0, 0, 0);
                acn = __builtin_amdgcn_mfma_i32_16x16x64_i8(an1, bf[s][1], acn, 0, 0, 0);
                mn = max(mn, max(max(acn[0], acn[1]), max(acn[2], acn[3])));
            }
        }
        #pragma unroll
        for (int off = 32; off > 0; off >>= 1) {
            mp = max(mp, __shfl_xor(mp, off));
            mn = max(mn, __shfl_xor(mn, off));
        }
        if (lane == 0) { smax[wid][sub][0] = (uint32_t)mp; smax[wid][sub][1] = (uint32_t)mn; }
    }
    __syncthreads();
    if (tid < NROW) {
        int sub = tid >> 1, sg = tid & 1;
        uint32_t m = max(max(smax[0][sub][sg], smax[1][sub][sg]),
                         max(smax[2][sub][sg], smax[3][sub][sg]));
        atomicMax(&maxv[tid], m);
    }
}

// ---------------------------------------------------------------------------
// k_lut: one block per (sub,sign) row. Build exact f64 table, then find
// integer (m,b) with floor((pr*m+b)/2^16) == code(pr) for ALL pr<=vmax.
// Integer feasibility <=> bit-exact correctness. Fallback: global LUT.
// ---------------------------------------------------------------------------
__global__ __launch_bounds__(256) void k_lut(const uint32_t* __restrict__ maxv,
                                             uint8_t* __restrict__ lut,
                                             uint2* __restrict__ mb,
                                             int* __restrict__ pmode) {
    int row = blockIdx.x, tid = threadIdx.x;
    __shared__ uint8_t codes[132];
    __shared__ int bestm;
    if (tid == 0) bestm = 0x7fffffff;
    int vmax = (int)maxv[row];
    for (int pr = tid; pr < 129; pr += 256) {
        double vmaxd = fmax((double)vmax, 1e-6);
        double step = vmaxd / 15.0;
        double q = rint((double)pr / step);
        q = fmin(fmax(q, 0.0), 15.0);
        codes[pr] = (uint8_t)q;
        lut[row * 132 + pr] = (uint8_t)q;
    }
    __syncthreads();
    int ve = max(vmax, 1);
    int m0 = (983040 + ve / 2) / ve;           // ~2^16*15/vmax
    int m = m0 - 128 + tid;
    if (m >= 1) {
        int L = 0, U = 0x7fffffff;
        for (int pr = 0; pr <= vmax && pr <= 128; ++pr) {
            int c = codes[pr];
            int lo = (c << 16) - pr * m;
            int hi = ((c + 1) << 16) - 1 - pr * m;
            L = max(L, lo);
            U = min(U, hi);
            if (L > U) break;
        }
        if (L <= U) atomicMin(&bestm, m);
    }
    __syncthreads();
    if (tid == 0) {
        if (bestm == 0x7fffffff) {
            pmode[row] = 1;
            mb[row] = make_uint2(0u, 0u);
        } else {
            int L = 0;
            for (int pr = 0; pr <= vmax && pr <= 128; ++pr)
                L = max(L, ((int)codes[pr] << 16) - pr * bestm);
            pmode[row] = 0;
            mb[row] = make_uint2((uint32_t)bestm, (uint32_t)L);
        }
    }
}

// ---------------------------------------------------------------------------
// Pass 2: same wave structure as k_max; integer-mad ADC (mad,bfe,lshl_add),
// exact integer weighted sums; f64 final scale. Epilogue: 4-wave LDS reduce.
// ---------------------------------------------------------------------------
__global__ __launch_bounds__(256, 3) void k_adc(const uint8_t* __restrict__ xq,
                                                const uint8_t* __restrict__ wqp,
                                                const uint8_t* __restrict__ wqn,
                                                const uint32_t* __restrict__ maxv,
                                                const uint8_t* __restrict__ lut,
                                                const uint2* __restrict__ mb,
                                                const int* __restrict__ pmode,
                                                const float* __restrict__ norm,
                                                float* __restrict__ out) {
    int tid = threadIdx.x, lane = tid & 63, wid = tid >> 6;
    int blk = blockIdx.x;
    int b = blk >> 9, ot = (blk >> 6) & 7, pt = blk & 63;
    int col = lane & 15, kq = lane >> 4;
    int p = pt * 16 + col, oa = ot * 16 + col;

    __shared__ int lred[4][64][4];

    const uint8_t* xbase = xq + (size_t)((b << 10) + p) * FTOT + kq * 16;
    const uint8_t* wpb = wqp + (size_t)oa * FTOT + kq * 16;
    const uint8_t* wnb = wqn + (size_t)oa * FTOT + kq * 16;

    int run[4] = {0, 0, 0, 0};
    for (int sub = 0; sub < NSUB; ++sub) {
        int fo = sub * 128;
        uint4 xg0 = *(const uint4*)(xbase + fo);
        uint4 xg1 = *(const uint4*)(xbase + fo + 64);
        v4i bf[NS][2];
        #pragma unroll
        for (int s = 0; s < NS; ++s) { bf[s][0] = bitsel(xg0, s); bf[s][1] = bitsel(xg1, s); }
        uint4 wp0 = *(const uint4*)(wpb + fo), wp1 = *(const uint4*)(wpb + fo + 64);
        uint4 wn0 = *(const uint4*)(wnb + fo), wn1 = *(const uint4*)(wnb + fo + 64);

        int rowp = sub * 2, rown = sub * 2 + 1;
        uint2 mbp = mb[rowp], mbn = mb[rown];
        int fbp = pmode[rowp], fbn = pmode[rown];
        const uint8_t* glp = lut + rowp * 132;
        const uint8_t* gln = lut + rown * 132;
        int vp = (int)maxv[rowp], vn = (int)maxv[rown];

        uint32_t Sp[4] = {0, 0, 0, 0}, Sn[4] = {0, 0, 0, 0};
        #pragma unroll
        for (int tt = 0; tt < 2; ++tt) {
            int t = wid * 2 + tt;
            v4i ap0 = bitsel(wp0, t), ap1 = bitsel(wp1, t);
            v4i an0 = bitsel(wn0, t), an1 = bitsel(wn1, t);
            #pragma unroll
            for (int s = 0; s < NS; ++s) {
                int st = s + t;
                v4i acc = {0, 0, 0, 0};
                acc = __builtin_amdgcn_mfma_i32_16x16x64_i8(ap0, bf[s][0], acc, 0, 0, 0);
                acc = __builtin_amdgcn_mfma_i32_16x16x64_i8(ap1, bf[s][1], acc, 0, 0, 0);
                if (fbp == 0) {
                    #pragma unroll
                    for (int i = 0; i < 4; ++i)
                        Sp[i] += (((__umul24((uint32_t)acc[i], mbp.x) + mbp.y) >> 16) & 15u) << st;
                } else {
                    #pragma unroll
                    for (int i = 0; i < 4; ++i) Sp[i] += (uint32_t)glp[acc[i]] << st;
                }
                v4i acn = {0, 0, 0, 0};
                acn = __builtin_amdgcn_mfma_i32_16x16x64_i8(an0, bf[s][0], acn, 0, 0, 0);
                acn = __builtin_amdgcn_mfma_i32_16x16x64_i8(an1, bf[s][1], acn, 0, 0, 0);
                if (fbn == 0) {
                    #pragma unroll
                    for (int i = 0; i < 4; ++i)
                        Sn[i] += (((__umul24((uint32_t)acn[i], mbn.x) + mbn.y) >> 16) & 15u) << st;
                } else {
                    #pragma unroll
                    for (int i = 0; i < 4; ++i) Sn[i] += (uint32_t)gln[acn[i]] << st;
                }
            }
        }
        #pragma unroll
        for (int i = 0; i < 4; ++i)
            run[i] += (int)__umul24((uint32_t)vp, Sp[i]) - (int)__umul24((uint32_t)vn, Sn[i]);
    }
    #pragma unroll
    for (int i = 0; i < 4; ++i) lred[wid][lane][i] = run[i];
    __syncthreads();
    {
        int lane2 = tid >> 2, i = tid & 3;
        long long s64 = 0;
        #pragma unroll
        for (int w2 = 0; w2 < 4; ++w2) s64 += (long long)lred[w2][lane2][i];
        int o = ot * 16 + (lane2 >> 4) * 4 + i;      // C/D: row=(lane>>4)*4+reg [m89]
        int pp2 = pt * 16 + (lane2 & 15);            // C/D: col=lane&15
        double v = (double)s64 * (double)norm[o] / 15.0 / 255.0 / 256.0;
        out[((size_t)(b * COUT_ + o)) * PP + pp2] = (float)v;
    }
    if (blk == 0 && tid == 0) out[(size_t)B_ * COUT_ * PP] = 0.0f;   // adc_loss
}

// ---------------------------------------------------------------------------
extern "C" void kernel_launch(void* const* d_in, const int* in_sizes, int n_in,
                              void* d_out, int out_size, void* d_ws, size_t ws_size,
                              hipStream_t stream) {
    const float* x = (const float*)d_in[0];
    const float* w = (const float*)d_in[1];
    float* out = (float*)d_out;
    char* ws = (char*)d_ws;

    float* norm = (float*)(ws + OFF_NORM);
    uint32_t* maxv = (uint32_t*)(ws + OFF_MAXV);
    uint2* mb = (uint2*)(ws + OFF_MB);
    int* pmode = (int*)(ws + OFF_PMODE);
    uint8_t* lut = (uint8_t*)(ws + OFF_LUT);
    uint8_t* wqp = (uint8_t*)(ws + OFF_WQP);
    uint8_t* wqn = (uint8_t*)(ws + OFF_WQN);
    uint8_t* xq  = (uint8_t*)(ws + OFF_XQ);

    k_prep_w<<<128, 256, 0, stream>>>(w, norm, wqp, wqn);
    k_prep_x<<<576, 256, 0, stream>>>(x, xq, maxv);
    k_max<<<1024, 256, 0, stream>>>(xq, wqp, wqn, maxv);
    k_lut<<<NROW, 256, 0, stream>>>(maxv, lut, mb, pmode);
    k_adc<<<1024, 256, 0, stream>>>(xq, wqp, wqn, maxv, lut, mb, pmode, norm, out);
}